// Round 1
// baseline (1212.261 us; speedup 1.0000x reference)
//
#include <hip/hip_runtime.h>

#define V_NUM 100000
#define E_NUM 50000
#define N_PAIRS 600000
#define DIM 128

// ---------------- Kernel 1: fused score matvecs ----------------
// One 64-lane wave per row. Rows [0,V_NUM) -> s_vt = v_fea@a_v + t_fea@a_t
// Rows [V_NUM, V_NUM+E_NUM) -> s_e = e_fea@a_e.
// Each lane loads float2 (8B) -> coalesced 512B per wave per matrix row.
__global__ void scores_kernel(const float* __restrict__ v_fea,
                              const float* __restrict__ t_fea,
                              const float* __restrict__ e_fea,
                              const float* __restrict__ a_v,
                              const float* __restrict__ a_t,
                              const float* __restrict__ a_e,
                              float* __restrict__ s_vt,
                              float* __restrict__ s_e) {
    const int wave = (int)((blockIdx.x * blockDim.x + threadIdx.x) >> 6);
    const int lane = (int)(threadIdx.x & 63);
    if (wave >= V_NUM + E_NUM) return;

    float partial;
    if (wave < V_NUM) {  // uniform per-wave branch
        const float2 vv = ((const float2*)(v_fea + (size_t)wave * DIM))[lane];
        const float2 tt = ((const float2*)(t_fea + (size_t)wave * DIM))[lane];
        const float2 wv = ((const float2*)a_v)[lane];
        const float2 wt = ((const float2*)a_t)[lane];
        partial = vv.x * wv.x + vv.y * wv.y + tt.x * wt.x + tt.y * wt.y;
    } else {
        const int r = wave - V_NUM;
        const float2 ee = ((const float2*)(e_fea + (size_t)r * DIM))[lane];
        const float2 we = ((const float2*)a_e)[lane];
        partial = ee.x * we.x + ee.y * we.y;
    }
    #pragma unroll
    for (int off = 32; off > 0; off >>= 1)
        partial += __shfl_xor(partial, off, 64);
    if (lane == 0) {
        if (wave < V_NUM) s_vt[wave] = partial;
        else s_e[wave - V_NUM] = partial;
    }
}

// ---------------- Kernel 2: per-pair exp + denom accumulation ----------------
// a = tanh(s_vt[v] + s_e[e]) / TAU ; TAU = 0.5 -> *2.
// Skip max-subtraction: a in (-2,2), exp(a) in [0.135, 7.39] -- safe, and
// w = ex/denom is mathematically identical.
__global__ void pair_pass1(const int* __restrict__ ve,
                           const float* __restrict__ s_vt,
                           const float* __restrict__ s_e,
                           float* __restrict__ exw,
                           float* __restrict__ denom) {
    const int p = (int)(blockIdx.x * blockDim.x + threadIdx.x);
    if (p >= N_PAIRS) return;
    const int2 pe = ((const int2*)ve)[p];
    const float a = tanhf(s_vt[pe.x] + s_e[pe.y]) * 2.0f;
    const float ex = __expf(a);
    exw[p] = ex;
    unsafeAtomicAdd(&denom[pe.x], ex);
}

// ---------------- Kernel 3: reciprocal of denom ----------------
__global__ void recip_kernel(float* __restrict__ denom) {
    const int i = (int)(blockIdx.x * blockDim.x + threadIdx.x);
    if (i >= V_NUM) return;
    const float d = denom[i];
    denom[i] = (d != 0.0f) ? (1.0f / d) : 0.0f;
}

// ---------------- Kernel 4: weighted scatter-aggregate ----------------
// 32 threads per pair; each thread handles 4 contiguous cols (float4 read of
// e_fea, 4 scalar f32 atomics into out). e_fea (25.6MB) is L2/L3 resident.
__global__ void pair_pass2(const int* __restrict__ ve,
                           const float* __restrict__ e_fea,
                           const float* __restrict__ exw,
                           const float* __restrict__ invdenom,
                           float* __restrict__ out) {
    const long long gid = (long long)blockIdx.x * blockDim.x + threadIdx.x;
    const int p = (int)(gid >> 5);
    if (p >= N_PAIRS) return;
    const int sub = (int)(gid & 31);
    const int2 pe = ((const int2*)ve)[p];
    const int v = pe.x, e = pe.y;
    const float w = exw[p] * invdenom[v];
    const float4 ef = ((const float4*)(e_fea + (size_t)e * DIM))[sub];
    float* o = out + (size_t)v * DIM + sub * 4;
    unsafeAtomicAdd(o + 0, w * ef.x);
    unsafeAtomicAdd(o + 1, w * ef.y);
    unsafeAtomicAdd(o + 2, w * ef.z);
    unsafeAtomicAdd(o + 3, w * ef.w);
}

extern "C" void kernel_launch(void* const* d_in, const int* in_sizes, int n_in,
                              void* d_out, int out_size, void* d_ws, size_t ws_size,
                              hipStream_t stream) {
    const float* v_fea = (const float*)d_in[0];
    const float* t_fea = (const float*)d_in[1];
    const float* e_fea = (const float*)d_in[2];
    const float* a_v   = (const float*)d_in[3];
    const float* a_t   = (const float*)d_in[4];
    const float* a_e   = (const float*)d_in[5];
    const int*   ve    = (const int*)d_in[6];
    float* out = (float*)d_out;

    // workspace layout (256B aligned)
    char* ws = (char*)d_ws;
    float* s_vt  = (float*)(ws);                      // V_NUM floats
    float* s_e   = (float*)(ws + 512 * 1024);         // E_NUM floats
    float* denom = (float*)(ws + 1024 * 1024);        // V_NUM floats
    float* exw   = (float*)(ws + 2048 * 1024);        // N_PAIRS floats

    // zero denom and out (harness poisons with 0xAA)
    hipMemsetAsync(denom, 0, V_NUM * sizeof(float), stream);
    hipMemsetAsync(out, 0, (size_t)out_size * sizeof(float), stream);

    // K1: scores
    {
        const int total_waves = V_NUM + E_NUM;
        const int threads = 256;
        const int blocks = (total_waves * 64 + threads - 1) / threads;
        scores_kernel<<<blocks, threads, 0, stream>>>(v_fea, t_fea, e_fea,
                                                      a_v, a_t, a_e, s_vt, s_e);
    }
    // K2: per-pair exp + denom atomics
    {
        const int threads = 256;
        const int blocks = (N_PAIRS + threads - 1) / threads;
        pair_pass1<<<blocks, threads, 0, stream>>>(ve, s_vt, s_e, exw, denom);
    }
    // K3: reciprocal
    {
        const int threads = 256;
        const int blocks = (V_NUM + threads - 1) / threads;
        recip_kernel<<<blocks, threads, 0, stream>>>(denom);
    }
    // K4: scatter-aggregate
    {
        const int threads = 256;
        const long long total = (long long)N_PAIRS * 32;
        const int blocks = (int)((total + threads - 1) / threads);
        pair_pass2<<<blocks, threads, 0, stream>>>(ve, e_fea, exw, denom, out);
    }
}

// Round 3
// 331.926 us; speedup vs baseline: 3.6522x; 3.6522x over previous
//
#include <hip/hip_runtime.h>

#define V_NUM 100000
#define E_NUM 50000
#define N_PAIRS 600000
#define DIM 128
#define SCAN_BLK 1024  // elements per scan block (256 threads x 4)
#define N_SCAN_BLOCKS ((V_NUM + SCAN_BLK - 1) / SCAN_BLK)  // 98

// ---------------- Kernel 1: fused score matvecs ----------------
// One 64-lane wave per row. Rows [0,V_NUM) -> s_vt = v_fea@a_v + t_fea@a_t
// Rows [V_NUM, V_NUM+E_NUM) -> s_e = e_fea@a_e.
__global__ void scores_kernel(const float* __restrict__ v_fea,
                              const float* __restrict__ t_fea,
                              const float* __restrict__ e_fea,
                              const float* __restrict__ a_v,
                              const float* __restrict__ a_t,
                              const float* __restrict__ a_e,
                              float* __restrict__ s_vt,
                              float* __restrict__ s_e) {
    const int wave = (int)((blockIdx.x * blockDim.x + threadIdx.x) >> 6);
    const int lane = (int)(threadIdx.x & 63);
    if (wave >= V_NUM + E_NUM) return;

    float partial;
    if (wave < V_NUM) {  // uniform per-wave branch
        const float2 vv = ((const float2*)(v_fea + (size_t)wave * DIM))[lane];
        const float2 tt = ((const float2*)(t_fea + (size_t)wave * DIM))[lane];
        const float2 wv = ((const float2*)a_v)[lane];
        const float2 wt = ((const float2*)a_t)[lane];
        partial = vv.x * wv.x + vv.y * wv.y + tt.x * wt.x + tt.y * wt.y;
    } else {
        const int r = wave - V_NUM;
        const float2 ee = ((const float2*)(e_fea + (size_t)r * DIM))[lane];
        const float2 we = ((const float2*)a_e)[lane];
        partial = ee.x * we.x + ee.y * we.y;
    }
    #pragma unroll
    for (int off = 32; off > 0; off >>= 1)
        partial += __shfl_xor(partial, off, 64);
    if (lane == 0) {
        if (wave < V_NUM) s_vt[wave] = partial;
        else s_e[wave - V_NUM] = partial;
    }
}

// ---------------- Kernel 2: histogram of v ----------------
__global__ void pair_hist(const int* __restrict__ ve, int* __restrict__ counts) {
    const int p = (int)(blockIdx.x * blockDim.x + threadIdx.x);
    if (p >= N_PAIRS) return;
    const int v = ((const int2*)ve)[p].x;
    atomicAdd(&counts[v], 1);
}

// ---------------- Kernel 3a: per-block exclusive scan of counts ----------------
// blk_scan[v] = exclusive prefix within its 1024-elem block; aux[b] = block total.
__global__ void scan_blocks(const int* __restrict__ counts,
                            int* __restrict__ blk_scan,
                            int* __restrict__ aux) {
    __shared__ int sdata[256];
    const int tid = (int)threadIdx.x;
    const int base = (int)blockIdx.x * SCAN_BLK + tid * 4;
    int4 c = make_int4(0, 0, 0, 0);
    if (base + 3 < V_NUM) {
        c = *(const int4*)(counts + base);
    } else {
        if (base + 0 < V_NUM) c.x = counts[base + 0];
        if (base + 1 < V_NUM) c.y = counts[base + 1];
        if (base + 2 < V_NUM) c.z = counts[base + 2];
        if (base + 3 < V_NUM) c.w = counts[base + 3];
    }
    const int s = c.x + c.y + c.z + c.w;
    sdata[tid] = s;
    __syncthreads();
    // Hillis-Steele inclusive scan over 256 thread sums
    #pragma unroll
    for (int off = 1; off < 256; off <<= 1) {
        const int val = (tid >= off) ? sdata[tid - off] : 0;
        __syncthreads();
        sdata[tid] += val;
        __syncthreads();
    }
    const int excl = sdata[tid] - s;
    if (tid == 255) aux[blockIdx.x] = sdata[255];
    const int e0 = excl;
    const int e1 = e0 + c.x;
    const int e2 = e1 + c.y;
    const int e3 = e2 + c.z;
    if (base + 3 < V_NUM) {
        *(int4*)(blk_scan + base) = make_int4(e0, e1, e2, e3);
    } else {
        if (base + 0 < V_NUM) blk_scan[base + 0] = e0;
        if (base + 1 < V_NUM) blk_scan[base + 1] = e1;
        if (base + 2 < V_NUM) blk_scan[base + 2] = e2;
    }
}

// ---------------- Kernel 3b: exclusive scan of the 98 block totals ----------------
__global__ void scan_aux(int* __restrict__ aux /* in: totals, out: exclusive scan */) {
    __shared__ int sdata[128];
    const int tid = (int)threadIdx.x;
    const int orig = (tid < N_SCAN_BLOCKS) ? aux[tid] : 0;
    sdata[tid] = orig;
    __syncthreads();
    #pragma unroll
    for (int off = 1; off < 128; off <<= 1) {
        const int val = (tid >= off) ? sdata[tid - off] : 0;
        __syncthreads();
        sdata[tid] += val;
        __syncthreads();
    }
    if (tid < N_SCAN_BLOCKS) aux[tid] = sdata[tid] - orig;  // exclusive
}

// ---------------- Kernel 4: scatter pairs into CSR order + compute exp ----------------
// a = tanh(s_vt[v] + s_e[e]) / 0.5. Max-subtraction dropped: a in (-2,2) so
// exp(a) in [0.135, 7.39]; w = ex/denom is identical.
__global__ void pair_scatter(const int* __restrict__ ve,
                             const float* __restrict__ s_vt,
                             const float* __restrict__ s_e,
                             const int* __restrict__ blk_scan,
                             const int* __restrict__ aux_scan,
                             int* __restrict__ cursor,
                             int* __restrict__ csr_e,
                             float* __restrict__ csr_ex) {
    const int p = (int)(blockIdx.x * blockDim.x + threadIdx.x);
    if (p >= N_PAIRS) return;
    const int2 pe = ((const int2*)ve)[p];
    const int v = pe.x, e = pe.y;
    const float a = tanhf(s_vt[v] + s_e[e]) * 2.0f;
    const float ex = __expf(a);
    const int start = blk_scan[v] + aux_scan[v >> 10];
    const int pos = start + atomicAdd(&cursor[v], 1);
    csr_e[pos] = e;
    csr_ex[pos] = ex;
}

// ---------------- Kernel 5: per-vertex softmax-weighted aggregate ----------------
// One wave per vertex: sum exp -> denom, then accumulate w * e_fea[e] into
// registers (2 floats/lane), single coalesced store. No output atomics.
__global__ void csr_aggregate(const int* __restrict__ counts,
                              const int* __restrict__ blk_scan,
                              const int* __restrict__ aux_scan,
                              const int* __restrict__ csr_e,
                              const float* __restrict__ csr_ex,
                              const float* __restrict__ e_fea,
                              float* __restrict__ out) {
    const int v = (int)((blockIdx.x * blockDim.x + threadIdx.x) >> 6);
    const int lane = (int)(threadIdx.x & 63);
    if (v >= V_NUM) return;
    const int start = blk_scan[v] + aux_scan[v >> 10];
    const int cnt = counts[v];

    float denom = 0.0f;
    for (int i = 0; i < cnt; ++i) denom += csr_ex[start + i];
    const float inv = (cnt > 0) ? (1.0f / denom) : 0.0f;

    float2 acc = make_float2(0.0f, 0.0f);
    for (int i = 0; i < cnt; ++i) {
        const int e = csr_e[start + i];
        const float w = csr_ex[start + i] * inv;
        const float2 ef = ((const float2*)(e_fea + (size_t)e * DIM))[lane];
        acc.x += w * ef.x;
        acc.y += w * ef.y;
    }
    ((float2*)(out + (size_t)v * DIM))[lane] = acc;
}

extern "C" void kernel_launch(void* const* d_in, const int* in_sizes, int n_in,
                              void* d_out, int out_size, void* d_ws, size_t ws_size,
                              hipStream_t stream) {
    const float* v_fea = (const float*)d_in[0];
    const float* t_fea = (const float*)d_in[1];
    const float* e_fea = (const float*)d_in[2];
    const float* a_v   = (const float*)d_in[3];
    const float* a_t   = (const float*)d_in[4];
    const float* a_e   = (const float*)d_in[5];
    const int*   ve    = (const int*)d_in[6];
    float* out = (float*)d_out;

    // ---- workspace layout (byte offsets, all 16B aligned) ----
    char* ws = (char*)d_ws;
    float* s_vt     = (float*)(ws + 0);                 // 400,000 B
    float* s_e      = (float*)(ws + 524288);            // 200,000 B
    int*   counts   = (int*)  (ws + 1048576);           // 400,000 B  } contiguous
    int*   cursor   = (int*)  (ws + 1048576 + 400000);  // 400,000 B  } single memset
    int*   blk_scan = (int*)  (ws + 2097152);           // 400,000 B
    int*   aux_scan = (int*)  (ws + 2097152 + 400000);  // 512 B
    int*   csr_e    = (int*)  (ws + 3145728);           // 2,400,000 B
    float* csr_ex   = (float*)(ws + 6291456);           // 2,400,000 B

    // zero counts + cursor in one shot (adjacent)
    hipMemsetAsync(counts, 0, 800000, stream);

    // K1: scores
    {
        const int total_waves = V_NUM + E_NUM;
        const int threads = 256;
        const int blocks = (total_waves * 64 + threads - 1) / threads;
        scores_kernel<<<blocks, threads, 0, stream>>>(v_fea, t_fea, e_fea,
                                                      a_v, a_t, a_e, s_vt, s_e);
    }
    // K2: histogram
    pair_hist<<<(N_PAIRS + 255) / 256, 256, 0, stream>>>(ve, counts);
    // K3: two-level exclusive scan
    scan_blocks<<<N_SCAN_BLOCKS, 256, 0, stream>>>(counts, blk_scan, aux_scan);
    scan_aux<<<1, 128, 0, stream>>>(aux_scan);
    // K4: scatter into CSR (+ exp)
    pair_scatter<<<(N_PAIRS + 255) / 256, 256, 0, stream>>>(
        ve, s_vt, s_e, blk_scan, aux_scan, cursor, csr_e, csr_ex);
    // K5: per-vertex aggregate (writes every out element -> no out memset)
    {
        const int threads = 256;
        const long long total = (long long)V_NUM * 64;
        const int blocks = (int)((total + threads - 1) / threads);
        csr_aggregate<<<blocks, threads, 0, stream>>>(
            counts, blk_scan, aux_scan, csr_e, csr_ex, e_fea, out);
    }
}